// Round 12
// baseline (316.355 us; speedup 1.0000x reference)
//
#include <hip/hip_runtime.h>

// Depthwise 3x3 conv, NHWC, stride 1, SAME, fp32.
// x: (32,112,112,192), w: (3,3,1,192), b: (192), out: (32,112,112,192)
//
// R12 = R11 + halo-ring depth fix (6 -> 10). Stage(t) writes halo rows
//      4t+6..4t+9; with depth 6 those aliased rows 4t..4t+3 consumed later
//      the same tile (the R11 correctness bug). Depth 10 matches the LDS
//      ring: row R's slot is recycled by row R+10 at stage(t_last(R)+1),
//      strictly after consume(t_last(R)).
//
//      Structure: 192-thread block = 16w x 12c4, HT=4, ring-10 rows x
//      3072 B = 30.7 KB LDS -> 5 blocks/CU. No w-halo in LDS (row = exactly
//      3 x 1KB chunks); edge threads (wi1 0/15) carry the neighbor column
//      in the register halo ring prefetched with the stage. One barrier per
//      tile: [vmcnt(4) -> barrier -> stage 4 rows -> consume -> NT stores].

constexpr int Bn = 32, Hn = 112, Wn = 112, Cn = 192, C4 = 48;
constexpr int WT = 16, CT = 12;       // 16 w-cols x 12 f4 = 48 channels
constexpr int WTiles = 7, CTiles = 4; // 48/12
constexpr int NSTEP = 7, HG = 4;      // 28 output rows per block
constexpr int ROWF4 = WT * CT;        // 192 f4 per staged row (= 3 chunks)
constexpr int ROWB = ROWF4 * 16;      // 3072 B
constexpr int RING = 10;              // 30720 B LDS; halo ring same depth

typedef float floatx4 __attribute__((ext_vector_type(4)));

#define VMWAIT(n) asm volatile("s_waitcnt vmcnt(" #n ")" ::: "memory")

__device__ __forceinline__ floatx4 fma4(floatx4 a, floatx4 b, floatx4 c) {
  c.x = fmaf(a.x, b.x, c.x);
  c.y = fmaf(a.y, b.y, c.y);
  c.z = fmaf(a.z, b.z, c.z);
  c.w = fmaf(a.w, b.w, c.w);
  return c;
}

__global__ __launch_bounds__(192, 4) void dwconv3x3_lean(
    const float* __restrict__ x,
    const float* __restrict__ wgt,   // (3,3,1,192)
    const float* __restrict__ bias,  // (192)
    float* __restrict__ out) {
  __shared__ floatx4 lds[RING * ROWF4];  // 30720 B
  const int tid = (int)threadIdx.x;
  const int lane = tid & 63;
  const int wave = tid >> 6;  // 0..2

  // Chunked XCD swizzle (3584 % 8 == 0).
  int bid = blockIdx.x;
  int chk = gridDim.x >> 3;  // 448
  int sbid = (bid & 7) * chk + (bid >> 3);
  int c4t = sbid & 3;  int tt = sbid >> 2;
  int wt = tt % WTiles; tt /= WTiles;
  int hg = tt & 3;      int b = tt >> 2;

  const int hbase = hg * 28;
  const int w0 = wt * WT;
  const int cbase = c4t * (CT * 4);
  const float* xb = x + (long)b * Hn * Wn * Cn;
  const int rstr = Wn * Cn;

  // Stage ownership. Row = 3 chunks of 1KB; 4-row step = 12 chunks, wave w
  // owns k = 4w..4w+3 (uniform 4/wave -> uniform vmcnt). Chunks never span
  // rows (192 f4 row = 3 x 64 f4 chunks exactly).
  int rr4[4], ck4[4], co4[4];
#pragma unroll
  for (int j = 0; j < 4; ++j) {
    int k = 4 * wave + j;
    rr4[j] = k / 3;  ck4[j] = k % 3;
    int rem = ck4[j] * 64 + lane;        // f4 index within row (0..191)
    int wi = rem / 12, c4l = rem % 12;
    co4[j] = (w0 + wi) * Cn + cbase + c4l * 4;  // always in-bounds (no halo)
  }
  // Prologue pair (rows 4,5) = 6 chunks, wave w owns 2w, 2w+1.
  int rr2[2], ck2[2], co2[2];
#pragma unroll
  for (int j = 0; j < 2; ++j) {
    int k = 2 * wave + j;
    rr2[j] = k / 3;  ck2[j] = k % 3;
    int rem = ck2[j] * 64 + lane;
    int wi = rem / 12, c4l = rem % 12;
    co2[j] = (w0 + wi) * Cn + cbase + c4l * 4;
  }

  // ---- Prologue stage: rows 0..3 (region map) + rows 4,5 (pair map).
#pragma unroll
  for (int j = 0; j < 4; ++j) {
    int h = max(hbase + rr4[j] - 1, 0);       // top clamp (hg==0, row 0)
    const float* src = xb + (long)h * rstr + co4[j];
    char* dst = (char*)lds + rr4[j] * ROWB + ck4[j] * 1024;
    __builtin_amdgcn_global_load_lds(
        (const __attribute__((address_space(1))) void*)src,
        (__attribute__((address_space(3))) void*)dst, 16, 0, 0);
  }
#pragma unroll
  for (int j = 0; j < 2; ++j) {
    int row = 4 + rr2[j];
    int h = hbase + row - 1;                  // 3..4+hbase, never OOB
    const float* src = xb + (long)h * rstr + co2[j];
    char* dst = (char*)lds + row * ROWB + ck2[j] * 1024;
    __builtin_amdgcn_global_load_lds(
        (const __attribute__((address_space(1))) void*)src,
        (__attribute__((address_space(3))) void*)dst, 16, 0, 0);
  }

  // ---- Per-thread roles.
  const int c4i = tid % 12;
  const int wi1 = tid / 12;            // 0..15
  const bool edgeL = (wi1 == 0), edgeR = (wi1 == 15);
  const bool edge = edgeL || edgeR;

  // Register halo ring (neighbor column, edge threads only; depth 10 to
  // match the LDS ring -- rows staged this tile must not alias rows still
  // to be consumed this tile).
  int hcol = edgeL ? (w0 - 1) : (w0 + WT);
  hcol = min(max(hcol, 0), Wn - 1);    // clamped; zero-weight kills garbage
  const float* hp = xb + (long)hcol * Cn + cbase + c4i * 4;
  floatx4 halo[RING];
  if (edge) {
#pragma unroll
    for (int r = 0; r < 6; ++r) {
      int h = max(hbase + r - 1, 0);
      halo[r] = *(const floatx4*)(hp + (long)h * rstr);
    }
  }

  // Weights with w-edge validity folded; bias.
  const int cofs = cbase + c4i * 4;
  const int wg1 = w0 + wi1;
  const float cs0 = (wg1 >= 1) ? 1.f : 0.f;
  const float cs2 = (wg1 <= Wn - 2) ? 1.f : 0.f;
  floatx4 wv[3][3];
#pragma unroll
  for (int kh = 0; kh < 3; ++kh) {
#pragma unroll
    for (int kw = 0; kw < 3; ++kw)
      wv[kh][kw] = *(const floatx4*)(wgt + (kh * 3 + kw) * Cn + cofs);
    wv[kh][0] *= cs0;
    wv[kh][2] *= cs2;
  }
  const floatx4 bv = *(const floatx4*)(bias + cofs);
  const float sTop = (hg == 0) ? 0.f : 1.f;       // staged row 0
  const float sBot = (hg == HG - 1) ? 0.f : 1.f;  // staged row 29

  const int ostr = Wn * C4;
  floatx4* outp = (floatx4*)out +
      ((long)(b * Hn + hbase) * Wn + wg1) * C4 + c4t * CT + c4i;

#pragma unroll
  for (int t = 0; t < NSTEP; ++t) {
    // Drain through stage(t-1) (rows needed this tile); keep last stores.
    if (t == 0) { VMWAIT(0); } else { VMWAIT(4); }
    __builtin_amdgcn_s_barrier();

    // Stage rows 4t+6..4t+9 (slots disjoint from this tile's consume set;
    // recycled slots were last read at consume(t-1), done before barrier).
    if (t < NSTEP - 1) {
#pragma unroll
      for (int j = 0; j < 4; ++j) {
        int row = 4 * t + 6 + rr4[j];
        int slot = row % RING;
        int h = min(hbase + row - 1, Hn - 1);   // bottom clamp only (h>=5)
        const float* src = xb + (long)h * rstr + co4[j];
        char* dst = (char*)lds + slot * ROWB + ck4[j] * 1024;
        __builtin_amdgcn_global_load_lds(
            (const __attribute__((address_space(1))) void*)src,
            (__attribute__((address_space(3))) void*)dst, 16, 0, 0);
      }
      if (edge) {
#pragma unroll
        for (int j = 0; j < 4; ++j) {
          int row = 4 * t + 6 + j;
          int h = min(hbase + row - 1, Hn - 1);
          halo[row % RING] = *(const floatx4*)(hp + (long)h * rstr);
        }
      }
    }

    // Consume staged rows 4t..4t+5 (all offsets compile-time post-unroll).
    floatx4 acc[4];
#pragma unroll
    for (int o = 0; o < 4; ++o) acc[o] = bv;

#pragma unroll
    for (int r = 0; r < 6; ++r) {
      const int row = 4 * t + r;
      const floatx4* base = lds + (row % RING) * ROWF4 + tid;
      floatx4 xv1 = base[0];
      floatx4 xv0 = base[edgeL ? 0 : -CT];
      floatx4 xv2 = base[edgeR ? 0 : CT];
      if (edgeL) xv0 = halo[row % RING];
      if (edgeR) xv2 = halo[row % RING];
      if (t == 0 && r == 0) { xv0 *= sTop; xv1 *= sTop; xv2 *= sTop; }
      if (t == NSTEP - 1 && r == 5) { xv0 *= sBot; xv1 *= sBot; xv2 *= sBot; }
#pragma unroll
      for (int kh = 0; kh < 3; ++kh) {
        int o = r - kh;
        if (o >= 0 && o < 4) {
          acc[o] = fma4(xv0, wv[kh][0], acc[o]);
          acc[o] = fma4(xv1, wv[kh][1], acc[o]);
          acc[o] = fma4(xv2, wv[kh][2], acc[o]);
        }
      }
    }

#pragma unroll
    for (int o = 0; o < 4; ++o)
      __builtin_nontemporal_store(acc[o], outp + (long)(4 * t + o) * ostr);
  }
}

extern "C" void kernel_launch(void* const* d_in, const int* in_sizes, int n_in,
                              void* d_out, int out_size, void* d_ws, size_t ws_size,
                              hipStream_t stream) {
  const float* x = (const float*)d_in[0];
  const float* w = (const float*)d_in[1];
  const float* b = (const float*)d_in[2];
  float* out = (float*)d_out;

  const int grid = Bn * HG * WTiles * CTiles;  // 3584, divisible by 8
  dwconv3x3_lean<<<grid, 192, 0, stream>>>(x, w, b, out);
}

// Round 13
// 107.788 us; speedup vs baseline: 2.9350x; 2.9350x over previous
//
#include <hip/hip_runtime.h>

// Depthwise 3x3 conv, NHWC, stride 1, SAME, fp32.
// x: (32,112,112,192), w: (3,3,1,192), b: (192), out: (32,112,112,192)
//
// R13: wave-private pipelines, ZERO barriers. Each wave owns an 8w x 8c4
//      patch and a private LDS ring; no cross-wave sharing -> correctness
//      is per-wave vmcnt/lgkmcnt only. Staged row = 10 cols (halo inline)
//      x 8 c4 = 1280 B; 4-row group = exactly 5 x 1KB chunks. Ring = 3
//      groups (15 KB/wave); 2-wave blocks = 30.7 KB -> 5 blocks/CU = 10
//      independent pipelines/CU, depth-2 group prefetch, counted vmcnt
//      {5,9,13,13,13,13,8} (never 0). Consume = lane-contiguous
//      ds_read_b128 (0-conflict family). lgkmcnt(0)+sched_barrier before
//      slot recycle.

constexpr int Bn = 32, Hn = 112, Wn = 112, Cn = 192, C4 = 48;
constexpr int PW = 8, PC = 8;          // per-wave patch: 8 cols x 8 f4
constexpr int WP = 14, CP = 6, HG = 4; // patch grid (w, c4, h-groups)
constexpr int NSTEP = 7;               // 4-row tiles per wave (28 rows)
constexpr int ROWB = 10 * PC * 16;     // 1280 B staged row (halo inline)
constexpr int GRPB = 5 * 1024;         // 4-row group = 5 chunks exactly
constexpr int WLDS = 3 * GRPB;         // 15360 B ring per wave

typedef float floatx4 __attribute__((ext_vector_type(4)));

#define VMWAIT(n) asm volatile("s_waitcnt vmcnt(" #n ")" ::: "memory")

__device__ __forceinline__ floatx4 fma4(floatx4 a, floatx4 b, floatx4 c) {
  c.x = fmaf(a.x, b.x, c.x);
  c.y = fmaf(a.y, b.y, c.y);
  c.z = fmaf(a.z, b.z, c.z);
  c.w = fmaf(a.w, b.w, c.w);
  return c;
}

__global__ __launch_bounds__(128, 2) void dwconv3x3_wavepriv(
    const float* __restrict__ x,
    const float* __restrict__ wgt,   // (3,3,1,192)
    const float* __restrict__ bias,  // (192)
    float* __restrict__ out) {
  __shared__ char lds[2 * WLDS];     // 30720 B -> 5 blocks/CU
  const int tid = (int)threadIdx.x;
  const int lane = tid & 63;
  const int wave = tid >> 6;

  // Chunked XCD swizzle (5376 % 8 == 0).
  int bid = blockIdx.x;
  int chk = gridDim.x >> 3;  // 672
  int sbid = (bid & 7) * chk + (bid >> 3);
  int pid = sbid * 2 + wave;           // wave-patch id, cp fastest
  int cp = pid % CP;  int t1 = pid / CP;
  int wp = t1 % WP;   t1 /= WP;
  int hg = t1 & 3;    int b = t1 >> 2;

  const int hbase = hg * 28;
  const int w0 = wp * PW;
  const float* xb = x + (long)b * Hn * Wn * Cn;
  const int rstr = Wn * Cn;
  char* wl = lds + wave * WLDS;

  // Per-chunk per-lane source mapping (group-invariant). Chunk k of a
  // group: f4 linear q = k*64+lane -> row q/80, col (q%80)/8, c4 q%8.
  int rowadd[5], coloff[5];
#pragma unroll
  for (int k = 0; k < 5; ++k) {
    int q = k * 64 + lane;
    rowadd[k] = q / 80;
    int rem = q % 80;
    int col = rem >> 3, c4 = rem & 7;
    int wc = min(max(w0 + col - 1, 0), Wn - 1);  // w-halo clamp (cs kills)
    coloff[k] = wc * Cn + cp * 32 + c4 * 4;
  }

  // Stage 4-row group g (staged rows 4g..4g+3; input h = hbase+row-1).
  auto stage = [&](int g) {
    char* dst0 = wl + (g % 3) * GRPB;
#pragma unroll
    for (int k = 0; k < 5; ++k) {
      int h = min(max(hbase + 4 * g + rowadd[k] - 1, 0), Hn - 1);
      const float* src = xb + (long)h * rstr + coloff[k];
      __builtin_amdgcn_global_load_lds(
          (const __attribute__((address_space(1))) void*)src,
          (__attribute__((address_space(3))) void*)(dst0 + k * 1024),
          16, 0, 0);
    }
  };

  // Prologue: groups 0..2 (15 loads in flight).
  stage(0); stage(1); stage(2);

  // Weights (L1-broadcast) with w-edge validity folded; bias.
  const int c4i = lane & 7;
  const int wi = lane >> 3;            // 0..7
  const int cofs = cp * 32 + c4i * 4;
  const int wg = w0 + wi;
  const float cs0 = (wg >= 1) ? 1.f : 0.f;
  const float cs2 = (wg <= Wn - 2) ? 1.f : 0.f;
  floatx4 wv[3][3];
#pragma unroll
  for (int kh = 0; kh < 3; ++kh) {
#pragma unroll
    for (int kw = 0; kw < 3; ++kw)
      wv[kh][kw] = *(const floatx4*)(wgt + (kh * 3 + kw) * Cn + cofs);
    wv[kh][0] *= cs0;
    wv[kh][2] *= cs2;
  }
  const floatx4 bv = *(const floatx4*)(bias + cofs);
  const float sTop = (hg == 0) ? 0.f : 1.f;       // staged row 0
  const float sBot = (hg == HG - 1) ? 0.f : 1.f;  // staged row 29

  const int ostr = Wn * C4;
  floatx4* outp = (floatx4*)out +
      ((long)(b * Hn + hbase) * Wn + wg) * C4 + cp * PC + c4i;

  // Tile t consumes staged rows 4t..4t+5 (groups t, t+1), then recycles
  // group t's slot with group t+3. vmcnt schedule (5 loads/group, 4
  // stores/tile, issue order g0 g1 g2 | [c0] g3 s0 | [c1] g4 s1 | ...):
  //   t=0 need g0,g1 keep g2            -> 5
  //   t=1 need g2    keep g3,s0         -> 9
  //   t=2..5 need g(t+1) keep s,g,s     -> 13
  //   t=6 need g7    keep s4,s5         -> 8
#pragma unroll
  for (int t = 0; t < NSTEP; ++t) {
    if (t == 0)      VMWAIT(5);
    else if (t == 1) VMWAIT(9);
    else if (t < 6)  VMWAIT(13);
    else             VMWAIT(8);

    floatx4 acc[4];
#pragma unroll
    for (int o = 0; o < 4; ++o) acc[o] = bv;

#pragma unroll
    for (int r = 0; r < 6; ++r) {
      const int s = 4 * t + r;
      const char* base =
          wl + (s >> 2) % 3 * GRPB + (s & 3) * ROWB + 128 + lane * 16;
      floatx4 xv0 = *(const floatx4*)(base - 128);
      floatx4 xv1 = *(const floatx4*)(base);
      floatx4 xv2 = *(const floatx4*)(base + 128);
      if (t == 0 && r == 0) { xv0 *= sTop; xv1 *= sTop; xv2 *= sTop; }
      if (t == NSTEP - 1 && r == 5) { xv0 *= sBot; xv1 *= sBot; xv2 *= sBot; }
#pragma unroll
      for (int kh = 0; kh < 3; ++kh) {
        int o = r - kh;
        if (o >= 0 && o < 4) {
          acc[o] = fma4(xv0, wv[kh][0], acc[o]);
          acc[o] = fma4(xv1, wv[kh][1], acc[o]);
          acc[o] = fma4(xv2, wv[kh][2], acc[o]);
        }
      }
    }

    // All this tile's ds_reads must retire before group t's slot is
    // overwritten by the stage below (wave-private: lgkmcnt suffices).
    asm volatile("s_waitcnt lgkmcnt(0)" ::: "memory");
    __builtin_amdgcn_sched_barrier(0);
    if (t <= 4) stage(t + 3);

#pragma unroll
    for (int o = 0; o < 4; ++o)
      __builtin_nontemporal_store(acc[o], outp + (long)(4 * t + o) * ostr);
  }
}

extern "C" void kernel_launch(void* const* d_in, const int* in_sizes, int n_in,
                              void* d_out, int out_size, void* d_ws, size_t ws_size,
                              hipStream_t stream) {
  const float* x = (const float*)d_in[0];
  const float* w = (const float*)d_in[1];
  const float* b = (const float*)d_in[2];
  float* out = (float*)d_out;

  const int grid = Bn * HG * WP * CP / 2;  // 5376 blocks, divisible by 8
  dwconv3x3_wavepriv<<<grid, 128, 0, stream>>>(x, w, b, out);
}